// Round 1
// baseline (12705.972 us; speedup 1.0000x reference)
//
#include <hip/hip_runtime.h>
#include <cstdint>
#include <cstddef>

// ---------------- types ----------------
typedef float    f32x4  __attribute__((ext_vector_type(4)));
typedef short    bf16x8 __attribute__((ext_vector_type(8)));
typedef uint16_t u16x4  __attribute__((ext_vector_type(4)));

// ---------------- problem dims ----------------
#define D_B 256
#define D_S 16
#define D_W 32
#define D_T 512      // S*W
#define D_V 30000
#define D_E 256
#define D_H 512
#define D_G 2048     // 4*H
#define D_C 5
#define NWG 64       // sequential-phase workgroups (j-split of gate rows)

// ---------------- workspace layout (bytes) ----------------
constexpr size_t OFF_EG    = 0;                                   // bf16 [V][2048]  (perm cols)
constexpr size_t OFF_EMB   = OFF_EG   + (size_t)D_V * D_G * 2;    // bf16 [V][256]
constexpr size_t OFF_WIH   = OFF_EMB  + (size_t)D_V * D_E * 2;    // bf16 perm [2048][256]
constexpr size_t OFF_WHH   = OFF_WIH  + (size_t)D_G * D_E * 2;    // bf16 perm [2048][512]
constexpr size_t OFF_BIAS  = OFF_WHH  + (size_t)D_G * D_H * 2;    // f32 perm [2048]
constexpr size_t OFF_HBUF  = OFF_BIAS + (size_t)D_G * 4;          // bf16 [2][256][1024] (hi|lo planes)
constexpr size_t OFF_FLAGS = OFF_HBUF + (size_t)2 * D_B * 2 * D_H * 2;
constexpr size_t OFF_REPS  = OFF_FLAGS + (size_t)64 * 32 * 4;     // f32 [16][256][512]
constexpr size_t OFF_A     = OFF_REPS + (size_t)D_S * D_B * D_H * 4;  // f32 [16][256][5]
constexpr size_t OFF_A0    = OFF_A    + (size_t)D_S * D_B * D_C * 4;  // f32 [3][256][5]

// ---------------- helpers ----------------
__device__ __forceinline__ uint16_t f2bf(float f) {
    uint32_t u = __builtin_bit_cast(uint32_t, f);
    u += 0x7FFFu + ((u >> 16) & 1u);          // RNE
    return (uint16_t)(u >> 16);
}
__device__ __forceinline__ float bf2f(uint16_t h) {
    return __builtin_bit_cast(float, (uint32_t)h << 16);
}
__device__ __forceinline__ float sigm(float x)  { return 1.0f / (1.0f + __expf(-x)); }
__device__ __forceinline__ float tanh_fast(float x) { return 1.0f - 2.0f / (__expf(2.0f * x) + 1.0f); }

// ======================================================================
// prep: convert emb/Wih/Whh to bf16 (weights row-permuted p = j*4+gate),
// build bias_perm, zero h-buffer parity 0 and flags.
// ======================================================================
__global__ __launch_bounds__(256) void prep_kernel(
    const float* __restrict__ emb, const float* __restrict__ Wih,
    const float* __restrict__ Whh, const float* __restrict__ bih,
    const float* __restrict__ bhh,
    uint16_t* __restrict__ embB, uint16_t* __restrict__ WihP,
    uint16_t* __restrict__ WhhP, float* __restrict__ biasP,
    uint16_t* __restrict__ hbuf0, int* __restrict__ flags)
{
    const long NA = (long)D_V * D_E / 4;   // emb float4 groups
    const long NB = (long)D_G * D_E / 4;   // Wih
    const long NC = (long)D_G * D_H / 4;   // Whh
    const long ND = D_G;                   // bias
    const long NE = (long)D_B * 2 * D_H / 8; // hbuf0 zero (8 ushorts per item)
    const long NF = 64;                    // flags
    const long TOT = NA + NB + NC + ND + NE + NF;
    long stride = (long)gridDim.x * blockDim.x;
    for (long i = (long)blockIdx.x * blockDim.x + threadIdx.x; i < TOT; i += stride) {
        if (i < NA) {
            f32x4 v = ((const f32x4*)emb)[i];
            u16x4 o = { f2bf(v[0]), f2bf(v[1]), f2bf(v[2]), f2bf(v[3]) };
            ((u16x4*)embB)[i] = o;
        } else if (i < NA + NB) {
            long j = i - NA; long flat = j * 4;
            int r = (int)(flat >> 8), e0 = (int)(flat & 255);
            int p = ((r & 511) << 2) | (r >> 9);
            f32x4 v = ((const f32x4*)Wih)[j];
            u16x4 o = { f2bf(v[0]), f2bf(v[1]), f2bf(v[2]), f2bf(v[3]) };
            *(u16x4*)(WihP + (size_t)p * D_E + e0) = o;
        } else if (i < NA + NB + NC) {
            long j = i - NA - NB; long flat = j * 4;
            int r = (int)(flat >> 9), k0 = (int)(flat & 511);
            int p = ((r & 511) << 2) | (r >> 9);
            f32x4 v = ((const f32x4*)Whh)[j];
            u16x4 o = { f2bf(v[0]), f2bf(v[1]), f2bf(v[2]), f2bf(v[3]) };
            *(u16x4*)(WhhP + (size_t)p * D_H + k0) = o;
        } else if (i < NA + NB + NC + ND) {
            int p = (int)(i - NA - NB - NC);
            int r = ((p & 3) << 9) | (p >> 2);
            biasP[p] = bih[r] + bhh[r];
        } else if (i < NA + NB + NC + ND + NE) {
            long j = i - NA - NB - NC - ND;
            u16x4 z = { 0, 0, 0, 0 };
            ((u16x4*)hbuf0)[j * 2]     = z;
            ((u16x4*)hbuf0)[j * 2 + 1] = z;
        } else {
            long j = i - NA - NB - NC - ND - NE;
            flags[j * 32] = 0;
        }
    }
}

// ======================================================================
// egemm: E_gates[v][p] = sum_e embB[v][e] * WihP[p][e]   (bf16 MFMA)
// M=30000 (tiles of 128, guarded), N=2048, K=256
// ======================================================================
__global__ __launch_bounds__(256) void egemm_kernel(
    const uint16_t* __restrict__ embB, const uint16_t* __restrict__ WihP,
    uint16_t* __restrict__ EG)
{
    int nt = blockIdx.x;            // 0..15
    int mt = blockIdx.y;            // 0..234
    int tid = threadIdx.x, lane = tid & 63, wv = tid >> 6;
    int v0 = mt * 128, n0 = nt * 128;
    __shared__ uint16_t As[128][40];
    __shared__ uint16_t Bs[128][40];
    f32x4 acc[4][4];
#pragma unroll
    for (int a = 0; a < 4; ++a)
#pragma unroll
        for (int bb = 0; bb < 4; ++bb) acc[a][bb] = (f32x4)0.0f;
    int wm = (wv >> 1) * 64, wn = (wv & 1) * 64;
    int row = tid >> 1, half = tid & 1;
    for (int kb = 0; kb < 8; ++kb) {
        int k0 = kb * 32;
        int vrow = v0 + row; if (vrow > D_V - 1) vrow = D_V - 1;
        const bf16x8* pa = (const bf16x8*)(embB + (size_t)vrow * D_E + k0 + half * 16);
        *(bf16x8*)&As[row][half * 16]     = pa[0];
        *(bf16x8*)&As[row][half * 16 + 8] = pa[1];
        const bf16x8* pb = (const bf16x8*)(WihP + (size_t)(n0 + row) * D_E + k0 + half * 16);
        *(bf16x8*)&Bs[row][half * 16]     = pb[0];
        *(bf16x8*)&Bs[row][half * 16 + 8] = pb[1];
        __syncthreads();
        int krow = (lane >> 4) * 8;
        bf16x8 af[4], bfr[4];
#pragma unroll
        for (int i = 0; i < 4; ++i) af[i]  = *(const bf16x8*)&As[wm + i * 16 + (lane & 15)][krow];
#pragma unroll
        for (int i = 0; i < 4; ++i) bfr[i] = *(const bf16x8*)&Bs[wn + i * 16 + (lane & 15)][krow];
#pragma unroll
        for (int mi = 0; mi < 4; ++mi)
#pragma unroll
            for (int ni = 0; ni < 4; ++ni)
                acc[mi][ni] = __builtin_amdgcn_mfma_f32_16x16x32_bf16(af[mi], bfr[ni], acc[mi][ni], 0, 0, 0);
        __syncthreads();
    }
#pragma unroll
    for (int mi = 0; mi < 4; ++mi) {
        int rbase = v0 + wm + mi * 16 + (lane >> 4) * 4;
#pragma unroll
        for (int ni = 0; ni < 4; ++ni) {
            int col = n0 + wn + ni * 16 + (lane & 15);
#pragma unroll
            for (int r = 0; r < 4; ++r) {
                int vr = rbase + r;
                if (vr < D_V) EG[(size_t)vr * D_G + col] = f2bf(acc[mi][ni][r]);
            }
        }
    }
}

// ======================================================================
// lstm_seq: 64 WGs, each owns 8 h-indices (32 perm gate rows).
// Whh slice resident in VGPRs; h exchanged as bf16 hi+lo via global dbuf;
// spin-sync on per-WG seqno flags (agent-scope atomics).
// ======================================================================
__global__ __launch_bounds__(256, 1) void lstm_seq_kernel(
    const int* __restrict__ abstracts, const uint16_t* __restrict__ EG,
    const uint16_t* __restrict__ WhhP, const float* __restrict__ biasP,
    uint16_t* __restrict__ hbuf, int* __restrict__ flags,
    float* __restrict__ reps)
{
    const int wg = blockIdx.x;                 // 0..63
    const int tid = threadIdx.x, lane = tid & 63, wv = tid >> 6;
    __shared__ float gfull[256][33];           // gates accumulate (pad 33 vs bank conflicts)
    __shared__ float c_st[8][256];
    __shared__ float rmax[8][256];
    __shared__ float bias_s[32];

    if (tid < 32) bias_s[tid] = biasP[wg * 32 + tid];
#pragma unroll
    for (int j = 0; j < 8; ++j) { c_st[j][tid] = 0.0f; rmax[j][tid] = -1e30f; }

    // resident B fragments: Whh slice [32 rows][512 k]
    const uint16_t* Wp = WhhP + (size_t)wg * 32 * D_H;
    bf16x8 bq[2][16];
#pragma unroll
    for (int nt = 0; nt < 2; ++nt)
#pragma unroll
        for (int ks = 0; ks < 16; ++ks)
            bq[nt][ks] = *(const bf16x8*)(Wp + (size_t)(nt * 16 + (lane & 15)) * D_H + ks * 32 + ((lane >> 4) * 8));
    __syncthreads();

    const int b = tid;  // 0..255
    for (int t = 0; t < D_T; ++t) {
        // ---- gather x-gates + bias into gfull[b][*] (h-independent; overlaps spin)
        int tok = abstracts[b * D_T + t];
        const uint16_t* eg = EG + (size_t)tok * D_G + wg * 32;
        bf16x8 g0 = *(const bf16x8*)(eg);
        bf16x8 g1 = *(const bf16x8*)(eg + 8);
        bf16x8 g2 = *(const bf16x8*)(eg + 16);
        bf16x8 g3 = *(const bf16x8*)(eg + 24);
#pragma unroll
        for (int i = 0; i < 8; ++i) gfull[b][i]      = bias_s[i]      + bf2f((uint16_t)g0[i]);
#pragma unroll
        for (int i = 0; i < 8; ++i) gfull[b][8 + i]  = bias_s[8 + i]  + bf2f((uint16_t)g1[i]);
#pragma unroll
        for (int i = 0; i < 8; ++i) gfull[b][16 + i] = bias_s[16 + i] + bf2f((uint16_t)g2[i]);
#pragma unroll
        for (int i = 0; i < 8; ++i) gfull[b][24 + i] = bias_s[24 + i] + bf2f((uint16_t)g3[i]);

        // ---- wait for h_t (wave 0 polls; others park at barrier)
        if (t > 0 && wv == 0) {
            int guard = 0;
            while (true) {
                int f = __hip_atomic_load(&flags[lane * 32], __ATOMIC_ACQUIRE, __HIP_MEMORY_SCOPE_AGENT);
                if (__all(f >= t)) break;
                if (++guard > 100000) break;   // bailout: wrong answer instead of hang
            }
        }
        __syncthreads();

        // ---- gates += Whh_slice @ h_t   (hi+lo split bf16)
        const uint16_t* cur = hbuf + (size_t)(t & 1) * (D_B * 2 * D_H);
        f32x4 acc[4][2];
#pragma unroll
        for (int m = 0; m < 4; ++m) { acc[m][0] = (f32x4)0.0f; acc[m][1] = (f32x4)0.0f; }
#pragma unroll
        for (int ks = 0; ks < 16; ++ks) {
#pragma unroll
            for (int mtt = 0; mtt < 4; ++mtt) {
                const uint16_t* rp = cur + (size_t)((wv * 4 + mtt) * 16 + (lane & 15)) * 1024 + ks * 32 + ((lane >> 4) * 8);
                bf16x8 ahi = *(const bf16x8*)rp;
                bf16x8 alo = *(const bf16x8*)(rp + 512);
                acc[mtt][0] = __builtin_amdgcn_mfma_f32_16x16x32_bf16(ahi, bq[0][ks], acc[mtt][0], 0, 0, 0);
                acc[mtt][1] = __builtin_amdgcn_mfma_f32_16x16x32_bf16(ahi, bq[1][ks], acc[mtt][1], 0, 0, 0);
                acc[mtt][0] = __builtin_amdgcn_mfma_f32_16x16x32_bf16(alo, bq[0][ks], acc[mtt][0], 0, 0, 0);
                acc[mtt][1] = __builtin_amdgcn_mfma_f32_16x16x32_bf16(alo, bq[1][ks], acc[mtt][1], 0, 0, 0);
            }
        }
        // ---- accumulate into gfull
#pragma unroll
        for (int mtt = 0; mtt < 4; ++mtt) {
            int br = (wv * 4 + mtt) * 16 + (lane >> 4) * 4;
#pragma unroll
            for (int nt = 0; nt < 2; ++nt) {
                int n = nt * 16 + (lane & 15);
#pragma unroll
                for (int r = 0; r < 4; ++r) gfull[br + r][n] += acc[mtt][nt][r];
            }
        }
        __syncthreads();

        // ---- pointwise LSTM cell + running max + h hi/lo store (thread = batch b)
        bf16x8 vhi, vlo;
#pragma unroll
        for (int j = 0; j < 8; ++j) {
            float gi = gfull[b][j * 4 + 0];
            float gf = gfull[b][j * 4 + 1];
            float gg = gfull[b][j * 4 + 2];
            float go = gfull[b][j * 4 + 3];
            float c2 = sigm(gf) * c_st[j][b] + sigm(gi) * tanh_fast(gg);
            float h2 = sigm(go) * tanh_fast(c2);
            c_st[j][b] = c2;
            float rm = fmaxf(rmax[j][b], h2);
            if ((t & 31) == 31) {
                reps[(size_t)(t >> 5) * (D_B * D_H) + (size_t)b * D_H + wg * 8 + j] = rm;
                rm = -1e30f;
            }
            rmax[j][b] = rm;
            uint16_t hhi = f2bf(h2);
            float lo = h2 - bf2f(hhi);
            vhi[j] = (short)hhi;
            vlo[j] = (short)f2bf(lo);
        }
        uint16_t* dst = hbuf + (size_t)((t + 1) & 1) * (D_B * 2 * D_H) + (size_t)b * 1024 + wg * 8;
        *(bf16x8*)dst = vhi;
        *(bf16x8*)(dst + 512) = vlo;
        __syncthreads();   // drains stores (vmcnt 0) before publish
        if (tid == 0)
            __hip_atomic_store(&flags[wg * 32], t + 1, __ATOMIC_RELEASE, __HIP_MEMORY_SCOPE_AGENT);
    }
}

// ======================================================================
// predA: A[s][b][c] = tanh(sum_{k<=min(s,2)} reps[s-k,b,:]·W1[k,:,c] + b1[c])
//        A0[s][b][c] (s<3, k=0 only).  One wave per (s,b).
// ======================================================================
__global__ __launch_bounds__(256) void predA_kernel(
    const float* __restrict__ reps, const float* __restrict__ W1,
    const float* __restrict__ b1, float* __restrict__ A, float* __restrict__ A0)
{
    int gw = blockIdx.x * 4 + (threadIdx.x >> 6);   // 0..4095
    int lane = threadIdx.x & 63;
    int s = gw >> 8, b = gw & 255;
    float accT[5] = {0, 0, 0, 0, 0};
    float acc0[5] = {0, 0, 0, 0, 0};
    for (int k = 0; k <= 2; ++k) {
        if (s - k < 0) break;
        const float* rp = reps + ((size_t)(s - k) * D_B + b) * D_H;
        const float* w  = W1 + (size_t)k * D_H * D_C;
        float part[5] = {0, 0, 0, 0, 0};
#pragma unroll
        for (int i = 0; i < 8; ++i) {
            int h = lane * 8 + i;
            float rv = rp[h];
#pragma unroll
            for (int c = 0; c < 5; ++c) part[c] += rv * w[h * 5 + c];
        }
#pragma unroll
        for (int c = 0; c < 5; ++c) { accT[c] += part[c]; if (k == 0) acc0[c] = part[c]; }
    }
#pragma unroll
    for (int m = 1; m < 64; m <<= 1)
#pragma unroll
        for (int c = 0; c < 5; ++c) {
            accT[c] += __shfl_xor(accT[c], m, 64);
            acc0[c] += __shfl_xor(acc0[c], m, 64);
        }
    if (lane == 0) {
#pragma unroll
        for (int c = 0; c < 5; ++c) A[((size_t)s * D_B + b) * D_C + c] = tanhf(accT[c] + b1[c]);
        if (s < 3)
#pragma unroll
            for (int c = 0; c < 5; ++c) A0[((size_t)s * D_B + b) * D_C + c] = tanhf(acc0[c] + b1[c]);
    }
}

// ======================================================================
// predOut: main i>=0: M[i] = sum_t A[t+i]@W2[t] + b2 ; fallback s<3 uses A0@W2[0]
// logsoftmax over C, write out[b][c][s]
// ======================================================================
__global__ __launch_bounds__(256) void predOut_kernel(
    const float* __restrict__ A, const float* __restrict__ A0,
    const float* __restrict__ W2, const float* __restrict__ b2,
    float* __restrict__ out)
{
    int g = blockIdx.x * 256 + threadIdx.x;   // 0..4095
    int b = g >> 4, s = g & 15;
    float v[5];
#pragma unroll
    for (int d = 0; d < 5; ++d) v[d] = b2[d];
    if (s < 3) {
        const float* Ar = A0 + ((size_t)s * D_B + b) * D_C;
#pragma unroll
        for (int c = 0; c < 5; ++c) {
            float a = Ar[c];
#pragma unroll
            for (int d = 0; d < 5; ++d) v[d] += a * W2[c * 5 + d];
        }
    } else {
        int i = s - 3;
        for (int tt = 0; tt < 4; ++tt) {
            const float* Ar = A + ((size_t)(tt + i) * D_B + b) * D_C;
            const float* w  = W2 + tt * 25;
#pragma unroll
            for (int c = 0; c < 5; ++c) {
                float a = Ar[c];
#pragma unroll
                for (int d = 0; d < 5; ++d) v[d] += a * w[c * 5 + d];
            }
        }
    }
    float m = v[0];
#pragma unroll
    for (int d = 1; d < 5; ++d) m = fmaxf(m, v[d]);
    float ssum = 0.0f;
#pragma unroll
    for (int d = 0; d < 5; ++d) ssum += expf(v[d] - m);
    float l = logf(ssum);
#pragma unroll
    for (int d = 0; d < 5; ++d) out[(size_t)b * 80 + d * 16 + s] = v[d] - m - l;
}

// ======================================================================
extern "C" void kernel_launch(void* const* d_in, const int* in_sizes, int n_in,
                              void* d_out, int out_size, void* d_ws, size_t ws_size,
                              hipStream_t stream)
{
    const int*   abstracts = (const int*)  d_in[0];
    const float* emb  = (const float*)d_in[1];
    const float* Wih  = (const float*)d_in[2];
    const float* Whh  = (const float*)d_in[3];
    const float* bih  = (const float*)d_in[4];
    const float* bhh  = (const float*)d_in[5];
    const float* W1   = (const float*)d_in[6];
    const float* b1   = (const float*)d_in[7];
    const float* W2   = (const float*)d_in[8];
    const float* b2   = (const float*)d_in[9];
    float* out = (float*)d_out;

    char* ws = (char*)d_ws;
    uint16_t* EG    = (uint16_t*)(ws + OFF_EG);
    uint16_t* embB  = (uint16_t*)(ws + OFF_EMB);
    uint16_t* WihP  = (uint16_t*)(ws + OFF_WIH);
    uint16_t* WhhP  = (uint16_t*)(ws + OFF_WHH);
    float*    biasP = (float*)   (ws + OFF_BIAS);
    uint16_t* hbuf  = (uint16_t*)(ws + OFF_HBUF);
    int*      flags = (int*)     (ws + OFF_FLAGS);
    float*    reps  = (float*)   (ws + OFF_REPS);
    float*    Abuf  = (float*)   (ws + OFF_A);
    float*    A0buf = (float*)   (ws + OFF_A0);

    prep_kernel<<<dim3(2048), dim3(256), 0, stream>>>(emb, Wih, Whh, bih, bhh,
                                                      embB, WihP, WhhP, biasP, hbuf, flags);
    egemm_kernel<<<dim3(16, 235), dim3(256), 0, stream>>>(embB, WihP, EG);
    lstm_seq_kernel<<<dim3(NWG), dim3(256), 0, stream>>>(abstracts, EG, WhhP, biasP,
                                                         hbuf, flags, reps);
    predA_kernel<<<dim3(1024), dim3(256), 0, stream>>>(reps, W1, b1, Abuf, A0buf);
    predOut_kernel<<<dim3(16), dim3(256), 0, stream>>>(Abuf, A0buf, W2, b2, out);
}

// Round 2
// 10233.464 us; speedup vs baseline: 1.2416x; 1.2416x over previous
//
#include <hip/hip_runtime.h>
#include <cstdint>
#include <cstddef>

// ---------------- types ----------------
typedef float    f32x4  __attribute__((ext_vector_type(4)));
typedef short    s16x8  __attribute__((ext_vector_type(8)));
typedef _Float16 f16x8  __attribute__((ext_vector_type(8)));
typedef uint16_t u16x4  __attribute__((ext_vector_type(4)));

// ---------------- problem dims ----------------
#define D_B 256
#define D_S 16
#define D_W 32
#define D_T 512      // S*W
#define D_V 30000
#define D_E 256
#define D_H 512
#define D_G 2048     // 4*H
#define D_C 5
#define NWG 64       // sequential-phase workgroups (j-split of gate rows)

// ---------------- workspace layout (bytes) ----------------
constexpr size_t OFF_EG    = 0;                                   // f16 [V][2048]  (perm cols)
constexpr size_t OFF_EMB   = OFF_EG   + (size_t)D_V * D_G * 2;    // f16 [V][256]
constexpr size_t OFF_WIH   = OFF_EMB  + (size_t)D_V * D_E * 2;    // f16 perm [2048][256]
constexpr size_t OFF_WHH   = OFF_WIH  + (size_t)D_G * D_E * 2;    // f16 perm [2048][512]
constexpr size_t OFF_BIAS  = OFF_WHH  + (size_t)D_G * D_H * 2;    // f32 perm [2048]
constexpr size_t OFF_HBUF  = OFF_BIAS + (size_t)D_G * 4;          // f16 [2][256][512]
constexpr size_t OFF_FLAGS = OFF_HBUF + (size_t)2 * D_B * D_H * 2;
constexpr size_t OFF_REPS  = OFF_FLAGS + (size_t)64 * 32 * 4;     // f32 [16][256][512]
constexpr size_t OFF_A     = OFF_REPS + (size_t)D_S * D_B * D_H * 4;  // f32 [16][256][5]
constexpr size_t OFF_A0    = OFF_A    + (size_t)D_S * D_B * D_C * 4;  // f32 [3][256][5]
constexpr size_t OFF_ABT   = OFF_A0   + (size_t)3 * D_B * D_C * 4;    // i32 [512][256]

// ---------------- helpers ----------------
__device__ __forceinline__ uint16_t f2h(float f) {
    _Float16 h = (_Float16)f;
    return __builtin_bit_cast(uint16_t, h);
}
__device__ __forceinline__ float sigm(float x)  { return 1.0f / (1.0f + __expf(-x)); }
__device__ __forceinline__ float tanh_fast(float x) { return 1.0f - 2.0f / (__expf(2.0f * x) + 1.0f); }

// one-shot cache maintenance (what acquire/release fences lower to, hoisted
// out of the poll loop): inv = discard stale L1/L2 so loads see LLC;
// wb = push dirty L2 lines to LLC before publishing the flag.
__device__ __forceinline__ void inv_caches() {
    asm volatile("buffer_inv sc1\n\ts_waitcnt vmcnt(0)" ::: "memory");
}
__device__ __forceinline__ void wb_l2() {
    asm volatile("buffer_wbl2 sc1\n\ts_waitcnt vmcnt(0)" ::: "memory");
}

// ======================================================================
// prep: convert emb/Wih/Whh to fp16 (weights row-permuted p = j*4+gate),
// build bias_perm, zero h-buffer parity 0 and flags, transpose abstracts.
// ======================================================================
__global__ __launch_bounds__(256) void prep_kernel(
    const int* __restrict__ abstracts,
    const float* __restrict__ emb, const float* __restrict__ Wih,
    const float* __restrict__ Whh, const float* __restrict__ bih,
    const float* __restrict__ bhh,
    uint16_t* __restrict__ embB, uint16_t* __restrict__ WihP,
    uint16_t* __restrict__ WhhP, float* __restrict__ biasP,
    uint16_t* __restrict__ hbuf0, int* __restrict__ flags,
    int* __restrict__ abT)
{
    const long NA = (long)D_V * D_E / 4;   // emb float4 groups
    const long NB = (long)D_G * D_E / 4;   // Wih
    const long NC = (long)D_G * D_H / 4;   // Whh
    const long ND = D_G;                   // bias
    const long NE = (long)D_B * D_H / 8;   // hbuf0 zero (8 halves per item)
    const long NF = 64;                    // flags
    const long NG = (long)D_T * D_B;       // abstracts transpose
    const long TOT = NA + NB + NC + ND + NE + NF + NG;
    long stride = (long)gridDim.x * blockDim.x;
    for (long i = (long)blockIdx.x * blockDim.x + threadIdx.x; i < TOT; i += stride) {
        if (i < NA) {
            f32x4 v = ((const f32x4*)emb)[i];
            u16x4 o = { f2h(v[0]), f2h(v[1]), f2h(v[2]), f2h(v[3]) };
            ((u16x4*)embB)[i] = o;
        } else if (i < NA + NB) {
            long j = i - NA; long flat = j * 4;
            int r = (int)(flat >> 8), e0 = (int)(flat & 255);
            int p = ((r & 511) << 2) | (r >> 9);
            f32x4 v = ((const f32x4*)Wih)[j];
            u16x4 o = { f2h(v[0]), f2h(v[1]), f2h(v[2]), f2h(v[3]) };
            *(u16x4*)(WihP + (size_t)p * D_E + e0) = o;
        } else if (i < NA + NB + NC) {
            long j = i - NA - NB; long flat = j * 4;
            int r = (int)(flat >> 9), k0 = (int)(flat & 511);
            int p = ((r & 511) << 2) | (r >> 9);
            f32x4 v = ((const f32x4*)Whh)[j];
            u16x4 o = { f2h(v[0]), f2h(v[1]), f2h(v[2]), f2h(v[3]) };
            *(u16x4*)(WhhP + (size_t)p * D_H + k0) = o;
        } else if (i < NA + NB + NC + ND) {
            int p = (int)(i - NA - NB - NC);
            int r = ((p & 3) << 9) | (p >> 2);
            biasP[p] = bih[r] + bhh[r];
        } else if (i < NA + NB + NC + ND + NE) {
            long j = i - NA - NB - NC - ND;
            u16x4 z = { 0, 0, 0, 0 };
            ((u16x4*)hbuf0)[j * 2]     = z;
            ((u16x4*)hbuf0)[j * 2 + 1] = z;
        } else if (i < NA + NB + NC + ND + NE + NF) {
            long j = i - NA - NB - NC - ND - NE;
            flags[j * 32] = 0;
        } else {
            long j = i - NA - NB - NC - ND - NE - NF;
            int t = (int)(j >> 8), b = (int)(j & 255);
            abT[(size_t)t * D_B + b] = abstracts[(size_t)b * D_T + t];
        }
    }
}

// ======================================================================
// egemm: E_gates[v][p] = sum_e embB[v][e] * WihP[p][e]   (fp16 MFMA)
// M=30000 (tiles of 128, guarded), N=2048, K=256
// ======================================================================
__global__ __launch_bounds__(256) void egemm_kernel(
    const uint16_t* __restrict__ embB, const uint16_t* __restrict__ WihP,
    uint16_t* __restrict__ EG)
{
    int nt = blockIdx.x;            // 0..15
    int mt = blockIdx.y;            // 0..234
    int tid = threadIdx.x, lane = tid & 63, wv = tid >> 6;
    int v0 = mt * 128, n0 = nt * 128;
    __shared__ uint16_t As[128][40];
    __shared__ uint16_t Bs[128][40];
    f32x4 acc[4][4];
#pragma unroll
    for (int a = 0; a < 4; ++a)
#pragma unroll
        for (int bb = 0; bb < 4; ++bb) acc[a][bb] = (f32x4)0.0f;
    int wm = (wv >> 1) * 64, wn = (wv & 1) * 64;
    int row = tid >> 1, half = tid & 1;
    for (int kb = 0; kb < 8; ++kb) {
        int k0 = kb * 32;
        int vrow = v0 + row; if (vrow > D_V - 1) vrow = D_V - 1;
        const s16x8* pa = (const s16x8*)(embB + (size_t)vrow * D_E + k0 + half * 16);
        *(s16x8*)&As[row][half * 16]     = pa[0];
        *(s16x8*)&As[row][half * 16 + 8] = pa[1];
        const s16x8* pb = (const s16x8*)(WihP + (size_t)(n0 + row) * D_E + k0 + half * 16);
        *(s16x8*)&Bs[row][half * 16]     = pb[0];
        *(s16x8*)&Bs[row][half * 16 + 8] = pb[1];
        __syncthreads();
        int krow = (lane >> 4) * 8;
        f16x8 af[4], bfr[4];
#pragma unroll
        for (int i = 0; i < 4; ++i) af[i]  = *(const f16x8*)&As[wm + i * 16 + (lane & 15)][krow];
#pragma unroll
        for (int i = 0; i < 4; ++i) bfr[i] = *(const f16x8*)&Bs[wn + i * 16 + (lane & 15)][krow];
#pragma unroll
        for (int mi = 0; mi < 4; ++mi)
#pragma unroll
            for (int ni = 0; ni < 4; ++ni)
                acc[mi][ni] = __builtin_amdgcn_mfma_f32_16x16x32_f16(af[mi], bfr[ni], acc[mi][ni], 0, 0, 0);
        __syncthreads();
    }
#pragma unroll
    for (int mi = 0; mi < 4; ++mi) {
        int rbase = v0 + wm + mi * 16 + (lane >> 4) * 4;
#pragma unroll
        for (int ni = 0; ni < 4; ++ni) {
            int col = n0 + wn + ni * 16 + (lane & 15);
#pragma unroll
            for (int r = 0; r < 4; ++r) {
                int vr = rbase + r;
                if (vr < D_V) EG[(size_t)vr * D_G + col] = f2h(acc[mi][ni][r]);
            }
        }
    }
}

// ======================================================================
// lstm_seq: 64 WGs, each owns 8 h-indices (32 perm gate rows).
// Whh slice resident in VGPRs; h exchanged as fp16 via global dbuf;
// spin-sync: RELAXED polls (LLC reads, no invalidate) + one inv per step
// on the consumer side, one wbl2 per step on the producer side.
// ======================================================================
__global__ __launch_bounds__(256, 1) void lstm_seq_kernel(
    const int* __restrict__ abT, const uint16_t* __restrict__ EG,
    const uint16_t* __restrict__ WhhP, const float* __restrict__ biasP,
    uint16_t* __restrict__ hbuf, int* __restrict__ flags,
    float* __restrict__ reps)
{
    const int wg = blockIdx.x;                 // 0..63
    const int tid = threadIdx.x, lane = tid & 63, wv = tid >> 6;
    __shared__ float gfull[256][33];           // gates accumulate (pad 33 vs bank conflicts)
    __shared__ float c_st[8][256];
    __shared__ float rmax[8][256];
    __shared__ float bias_s[32];

    if (tid < 32) bias_s[tid] = biasP[wg * 32 + tid];
#pragma unroll
    for (int j = 0; j < 8; ++j) { c_st[j][tid] = 0.0f; rmax[j][tid] = -1e30f; }

    // resident B fragments: Whh slice [32 rows][512 k] fp16
    const uint16_t* Wp = WhhP + (size_t)wg * 32 * D_H;
    f16x8 bq[2][16];
#pragma unroll
    for (int nt = 0; nt < 2; ++nt)
#pragma unroll
        for (int ks = 0; ks < 16; ++ks)
            bq[nt][ks] = *(const f16x8*)(Wp + (size_t)(nt * 16 + (lane & 15)) * D_H + ks * 32 + ((lane >> 4) * 8));
    __syncthreads();

    const int b = tid;  // 0..255
    for (int t = 0; t < D_T; ++t) {
        // ---- gather x-gates + bias into gfull[b][*] (h-independent; overlaps spin)
        int tok = abT[(size_t)t * D_B + b];
        const uint16_t* eg = EG + (size_t)tok * D_G + wg * 32;
        f16x8 g0 = *(const f16x8*)(eg);
        f16x8 g1 = *(const f16x8*)(eg + 8);
        f16x8 g2 = *(const f16x8*)(eg + 16);
        f16x8 g3 = *(const f16x8*)(eg + 24);
#pragma unroll
        for (int i = 0; i < 8; ++i) gfull[b][i]      = bias_s[i]      + (float)g0[i];
#pragma unroll
        for (int i = 0; i < 8; ++i) gfull[b][8 + i]  = bias_s[8 + i]  + (float)g1[i];
#pragma unroll
        for (int i = 0; i < 8; ++i) gfull[b][16 + i] = bias_s[16 + i] + (float)g2[i];
#pragma unroll
        for (int i = 0; i < 8; ++i) gfull[b][24 + i] = bias_s[24 + i] + (float)g3[i];

        // ---- wait for h_t: RELAXED polls (no per-iteration cache inv),
        //      then ONE inv so subsequent cached loads see fresh LLC data.
        if (t > 0 && wv == 0) {
            int guard = 0;
            while (true) {
                int f = __hip_atomic_load(&flags[lane * 32], __ATOMIC_RELAXED, __HIP_MEMORY_SCOPE_AGENT);
                if (__all(f >= t)) break;
                if (++guard > 100000) break;   // bailout: wrong answer instead of hang
            }
            inv_caches();
        }
        __syncthreads();

        // ---- gates += Whh_slice @ h_t   (single fp16)
        const uint16_t* cur = hbuf + (size_t)(t & 1) * (D_B * D_H);
        f32x4 acc[4][2];
#pragma unroll
        for (int m = 0; m < 4; ++m) { acc[m][0] = (f32x4)0.0f; acc[m][1] = (f32x4)0.0f; }
#pragma unroll
        for (int ks = 0; ks < 16; ++ks) {
#pragma unroll
            for (int mtt = 0; mtt < 4; ++mtt) {
                const uint16_t* rp = cur + (size_t)((wv * 4 + mtt) * 16 + (lane & 15)) * D_H + ks * 32 + ((lane >> 4) * 8);
                f16x8 ah = *(const f16x8*)rp;
                acc[mtt][0] = __builtin_amdgcn_mfma_f32_16x16x32_f16(ah, bq[0][ks], acc[mtt][0], 0, 0, 0);
                acc[mtt][1] = __builtin_amdgcn_mfma_f32_16x16x32_f16(ah, bq[1][ks], acc[mtt][1], 0, 0, 0);
            }
        }
        // ---- accumulate into gfull
#pragma unroll
        for (int mtt = 0; mtt < 4; ++mtt) {
            int br = (wv * 4 + mtt) * 16 + (lane >> 4) * 4;
#pragma unroll
            for (int nt = 0; nt < 2; ++nt) {
                int n = nt * 16 + (lane & 15);
#pragma unroll
                for (int r = 0; r < 4; ++r) gfull[br + r][n] += acc[mtt][nt][r];
            }
        }
        __syncthreads();

        // ---- pointwise LSTM cell + running max + h store (thread = batch b)
        f16x8 vh;
#pragma unroll
        for (int j = 0; j < 8; ++j) {
            float gi = gfull[b][j * 4 + 0];
            float gf = gfull[b][j * 4 + 1];
            float gg = gfull[b][j * 4 + 2];
            float go = gfull[b][j * 4 + 3];
            float c2 = sigm(gf) * c_st[j][b] + sigm(gi) * tanh_fast(gg);
            float h2 = sigm(go) * tanh_fast(c2);
            c_st[j][b] = c2;
            float rm = fmaxf(rmax[j][b], h2);
            if ((t & 31) == 31) {
                reps[(size_t)(t >> 5) * (D_B * D_H) + (size_t)b * D_H + wg * 8 + j] = rm;
                rm = -1e30f;
            }
            rmax[j][b] = rm;
            vh[j] = (_Float16)h2;
        }
        uint16_t* dst = hbuf + (size_t)((t + 1) & 1) * (D_B * D_H) + (size_t)b * D_H + wg * 8;
        *(f16x8*)dst = vh;
        __syncthreads();   // drains stores (vmcnt 0) before publish
        if (tid == 0) {
            wb_l2();       // push dirty h lines to LLC before the flag
            __hip_atomic_store(&flags[wg * 32], t + 1, __ATOMIC_RELAXED, __HIP_MEMORY_SCOPE_AGENT);
        }
    }
}

// ======================================================================
// predA: A[s][b][c] = tanh(sum_{k<=min(s,2)} reps[s-k,b,:]·W1[k,:,c] + b1[c])
//        A0[s][b][c] (s<3, k=0 only).  One wave per (s,b).
// ======================================================================
__global__ __launch_bounds__(256) void predA_kernel(
    const float* __restrict__ reps, const float* __restrict__ W1,
    const float* __restrict__ b1, float* __restrict__ A, float* __restrict__ A0)
{
    int gw = blockIdx.x * 4 + (threadIdx.x >> 6);   // 0..4095
    int lane = threadIdx.x & 63;
    int s = gw >> 8, b = gw & 255;
    float accT[5] = {0, 0, 0, 0, 0};
    float acc0[5] = {0, 0, 0, 0, 0};
    for (int k = 0; k <= 2; ++k) {
        if (s - k < 0) break;
        const float* rp = reps + ((size_t)(s - k) * D_B + b) * D_H;
        const float* w  = W1 + (size_t)k * D_H * D_C;
        float part[5] = {0, 0, 0, 0, 0};
#pragma unroll
        for (int i = 0; i < 8; ++i) {
            int h = lane * 8 + i;
            float rv = rp[h];
#pragma unroll
            for (int c = 0; c < 5; ++c) part[c] += rv * w[h * 5 + c];
        }
#pragma unroll
        for (int c = 0; c < 5; ++c) { accT[c] += part[c]; if (k == 0) acc0[c] = part[c]; }
    }
#pragma unroll
    for (int m = 1; m < 64; m <<= 1)
#pragma unroll
        for (int c = 0; c < 5; ++c) {
            accT[c] += __shfl_xor(accT[c], m, 64);
            acc0[c] += __shfl_xor(acc0[c], m, 64);
        }
    if (lane == 0) {
#pragma unroll
        for (int c = 0; c < 5; ++c) A[((size_t)s * D_B + b) * D_C + c] = tanhf(accT[c] + b1[c]);
        if (s < 3)
#pragma unroll
            for (int c = 0; c < 5; ++c) A0[((size_t)s * D_B + b) * D_C + c] = tanhf(acc0[c] + b1[c]);
    }
}

// ======================================================================
// predOut: main i>=0: M[i] = sum_t A[t+i]@W2[t] + b2 ; fallback s<3 uses A0@W2[0]
// logsoftmax over C, write out[b][c][s]
// ======================================================================
__global__ __launch_bounds__(256) void predOut_kernel(
    const float* __restrict__ A, const float* __restrict__ A0,
    const float* __restrict__ W2, const float* __restrict__ b2,
    float* __restrict__ out)
{
    int g = blockIdx.x * 256 + threadIdx.x;   // 0..4095
    int b = g >> 4, s = g & 15;
    float v[5];
#pragma unroll
    for (int d = 0; d < 5; ++d) v[d] = b2[d];
    if (s < 3) {
        const float* Ar = A0 + ((size_t)s * D_B + b) * D_C;
#pragma unroll
        for (int c = 0; c < 5; ++c) {
            float a = Ar[c];
#pragma unroll
            for (int d = 0; d < 5; ++d) v[d] += a * W2[c * 5 + d];
        }
    } else {
        int i = s - 3;
        for (int tt = 0; tt < 4; ++tt) {
            const float* Ar = A + ((size_t)(tt + i) * D_B + b) * D_C;
            const float* w  = W2 + tt * 25;
#pragma unroll
            for (int c = 0; c < 5; ++c) {
                float a = Ar[c];
#pragma unroll
                for (int d = 0; d < 5; ++d) v[d] += a * w[c * 5 + d];
            }
        }
    }
    float m = v[0];
#pragma unroll
    for (int d = 1; d < 5; ++d) m = fmaxf(m, v[d]);
    float ssum = 0.0f;
#pragma unroll
    for (int d = 0; d < 5; ++d) ssum += expf(v[d] - m);
    float l = logf(ssum);
#pragma unroll
    for (int d = 0; d < 5; ++d) out[(size_t)b * 80 + d * 16 + s] = v[d] - m - l;
}

// ======================================================================
extern "C" void kernel_launch(void* const* d_in, const int* in_sizes, int n_in,
                              void* d_out, int out_size, void* d_ws, size_t ws_size,
                              hipStream_t stream)
{
    const int*   abstracts = (const int*)  d_in[0];
    const float* emb  = (const float*)d_in[1];
    const float* Wih  = (const float*)d_in[2];
    const float* Whh  = (const float*)d_in[3];
    const float* bih  = (const float*)d_in[4];
    const float* bhh  = (const float*)d_in[5];
    const float* W1   = (const float*)d_in[6];
    const float* b1   = (const float*)d_in[7];
    const float* W2   = (const float*)d_in[8];
    const float* b2   = (const float*)d_in[9];
    float* out = (float*)d_out;

    char* ws = (char*)d_ws;
    uint16_t* EG    = (uint16_t*)(ws + OFF_EG);
    uint16_t* embB  = (uint16_t*)(ws + OFF_EMB);
    uint16_t* WihP  = (uint16_t*)(ws + OFF_WIH);
    uint16_t* WhhP  = (uint16_t*)(ws + OFF_WHH);
    float*    biasP = (float*)   (ws + OFF_BIAS);
    uint16_t* hbuf  = (uint16_t*)(ws + OFF_HBUF);
    int*      flags = (int*)     (ws + OFF_FLAGS);
    float*    reps  = (float*)   (ws + OFF_REPS);
    float*    Abuf  = (float*)   (ws + OFF_A);
    float*    A0buf = (float*)   (ws + OFF_A0);
    int*      abT   = (int*)     (ws + OFF_ABT);

    prep_kernel<<<dim3(2048), dim3(256), 0, stream>>>(abstracts, emb, Wih, Whh, bih, bhh,
                                                      embB, WihP, WhhP, biasP, hbuf, flags, abT);
    egemm_kernel<<<dim3(16, 235), dim3(256), 0, stream>>>(embB, WihP, EG);
    lstm_seq_kernel<<<dim3(NWG), dim3(256), 0, stream>>>(abT, EG, WhhP, biasP,
                                                         hbuf, flags, reps);
    predA_kernel<<<dim3(1024), dim3(256), 0, stream>>>(reps, W1, b1, Abuf, A0buf);
    predOut_kernel<<<dim3(16), dim3(256), 0, stream>>>(Abuf, A0buf, W2, b2, out);
}

// Round 4
// 4765.578 us; speedup vs baseline: 2.6662x; 2.1474x over previous
//
#include <hip/hip_runtime.h>
#include <cstdint>
#include <cstddef>

// ---------------- types ----------------
typedef float    f32x4  __attribute__((ext_vector_type(4)));
typedef short    s16x8  __attribute__((ext_vector_type(8)));
typedef _Float16 f16x8  __attribute__((ext_vector_type(8)));
typedef uint16_t u16x4  __attribute__((ext_vector_type(4)));

// ---------------- problem dims ----------------
#define D_B 256
#define D_S 16
#define D_W 32
#define D_T 512      // S*W
#define D_V 30000
#define D_E 256
#define D_H 512
#define D_G 2048     // 4*H
#define D_C 5
#define NWG 64       // sequential-phase workgroups (j-split of gate rows)

// ---------------- workspace layout (bytes) ----------------
constexpr size_t OFF_EG    = 0;                                   // f16 [V][2048]  (perm cols)
constexpr size_t OFF_EMB   = OFF_EG   + (size_t)D_V * D_G * 2;    // f16 [V][256]
constexpr size_t OFF_WIH   = OFF_EMB  + (size_t)D_V * D_E * 2;    // f16 perm [2048][256]
constexpr size_t OFF_WHH   = OFF_WIH  + (size_t)D_G * D_E * 2;    // f16 perm [2048][512]
constexpr size_t OFF_BIAS  = OFF_WHH  + (size_t)D_G * D_H * 2;    // f32 perm [2048]
constexpr size_t OFF_HBUF  = OFF_BIAS + (size_t)D_G * 4;          // f16 [2][256][512]
constexpr size_t OFF_FLAGS = OFF_HBUF + (size_t)2 * D_B * D_H * 2; // i32 [4 wv][64 wg]
constexpr size_t OFF_REPS  = OFF_FLAGS + (size_t)256 * 4;         // f32 [16][256][512]
constexpr size_t OFF_A     = OFF_REPS + (size_t)D_S * D_B * D_H * 4;  // f32 [16][256][5]
constexpr size_t OFF_A0    = OFF_A    + (size_t)D_S * D_B * D_C * 4;  // f32 [3][256][5]
constexpr size_t OFF_ABT   = OFF_A0   + (size_t)3 * D_B * D_C * 4;    // i32 [512][256]

// ---------------- helpers ----------------
__device__ __forceinline__ uint16_t f2h(float f) {
    _Float16 h = (_Float16)f;
    return __builtin_bit_cast(uint16_t, h);
}
__device__ __forceinline__ float sigm(float x)  { return 1.0f / (1.0f + __expf(-x)); }
__device__ __forceinline__ float tanh_fast(float x) { return 1.0f - 2.0f / (__expf(2.0f * x) + 1.0f); }

// ---- LLC-coherent (cross-XCD) access: sc0 sc1 bypasses L1+L2 per access.
// The LLC copy is the single point of truth for hbuf/flags; NOTHING may
// touch those regions through the cached path (no dirty L2 copies anywhere).
__device__ __forceinline__ int load_flag_llc(const int* p) {
    int v;
    asm volatile("global_load_dword %0, %1, off sc0 sc1\n\ts_waitcnt vmcnt(0)"
                 : "=v"(v) : "v"(p) : "memory");
    return v;
}
__device__ __forceinline__ void store_flag_llc(int* p, int v) {
    asm volatile("global_store_dword %0, %1, off sc0 sc1" :: "v"(p), "v"(v) : "memory");
}
__device__ __forceinline__ void store_dword_llc(int* p, int v) {
    asm volatile("global_store_dword %0, %1, off sc0 sc1" :: "v"(p), "v"(v) : "memory");
}
__device__ __forceinline__ void store16_llc(void* p, f32x4 v) {
    asm volatile("global_store_dwordx4 %0, %1, off sc0 sc1" :: "v"(p), "v"(v) : "memory");
}
__device__ __forceinline__ void store_h_llc(uint16_t* p, f16x8 v) {
    asm volatile("global_store_dwordx4 %0, %1, off sc0 sc1\n\ts_waitcnt vmcnt(0)"
                 :: "v"(p), "v"(v) : "memory");
}
// 16 batched LLC loads (one m-tile of h A-fragments) + single wait.
// EARLY-CLOBBER outputs ("=&v"): the first load writes its dest while the
// base pair is still live for the other 15 — outputs must not overlap input.
__device__ __forceinline__ void load_h16_llc(const uint16_t* base, f16x8* A) {
    asm volatile(
        "global_load_dwordx4 %0,  %16, off sc0 sc1\n\t"
        "global_load_dwordx4 %1,  %16, off offset:64 sc0 sc1\n\t"
        "global_load_dwordx4 %2,  %16, off offset:128 sc0 sc1\n\t"
        "global_load_dwordx4 %3,  %16, off offset:192 sc0 sc1\n\t"
        "global_load_dwordx4 %4,  %16, off offset:256 sc0 sc1\n\t"
        "global_load_dwordx4 %5,  %16, off offset:320 sc0 sc1\n\t"
        "global_load_dwordx4 %6,  %16, off offset:384 sc0 sc1\n\t"
        "global_load_dwordx4 %7,  %16, off offset:448 sc0 sc1\n\t"
        "global_load_dwordx4 %8,  %16, off offset:512 sc0 sc1\n\t"
        "global_load_dwordx4 %9,  %16, off offset:576 sc0 sc1\n\t"
        "global_load_dwordx4 %10, %16, off offset:640 sc0 sc1\n\t"
        "global_load_dwordx4 %11, %16, off offset:704 sc0 sc1\n\t"
        "global_load_dwordx4 %12, %16, off offset:768 sc0 sc1\n\t"
        "global_load_dwordx4 %13, %16, off offset:832 sc0 sc1\n\t"
        "global_load_dwordx4 %14, %16, off offset:896 sc0 sc1\n\t"
        "global_load_dwordx4 %15, %16, off offset:960 sc0 sc1\n\t"
        "s_waitcnt vmcnt(0)"
        : "=&v"(A[0]), "=&v"(A[1]), "=&v"(A[2]), "=&v"(A[3]),
          "=&v"(A[4]), "=&v"(A[5]), "=&v"(A[6]), "=&v"(A[7]),
          "=&v"(A[8]), "=&v"(A[9]), "=&v"(A[10]), "=&v"(A[11]),
          "=&v"(A[12]), "=&v"(A[13]), "=&v"(A[14]), "=&v"(A[15])
        : "v"(base) : "memory");
}

// ======================================================================
// prep: convert emb/Wih/Whh to fp16 (weights row-permuted p = j*4+gate),
// build bias_perm, transpose abstracts. hbuf parity-0 and flags are
// zeroed via sc0 sc1 WRITE-THROUGH stores (LLC authoritative — lstm reads
// them with sc0 sc1 loads and must see these zeros on every call/replay).
// ======================================================================
__global__ __launch_bounds__(256) void prep_kernel(
    const int* __restrict__ abstracts,
    const float* __restrict__ emb, const float* __restrict__ Wih,
    const float* __restrict__ Whh, const float* __restrict__ bih,
    const float* __restrict__ bhh,
    uint16_t* __restrict__ embB, uint16_t* __restrict__ WihP,
    uint16_t* __restrict__ WhhP, float* __restrict__ biasP,
    uint16_t* __restrict__ hbuf0, int* __restrict__ flags,
    int* __restrict__ abT)
{
    const long NA = (long)D_V * D_E / 4;   // emb float4 groups
    const long NB = (long)D_G * D_E / 4;   // Wih
    const long NC = (long)D_G * D_H / 4;   // Whh
    const long ND = D_G;                   // bias
    const long NE = (long)D_B * D_H / 8;   // hbuf0 zero (16B per item, LLC)
    const long NF = 256;                   // flags (LLC)
    const long NG = (long)D_T * D_B;       // abstracts transpose
    const long TOT = NA + NB + NC + ND + NE + NF + NG;
    long stride = (long)gridDim.x * blockDim.x;
    for (long i = (long)blockIdx.x * blockDim.x + threadIdx.x; i < TOT; i += stride) {
        if (i < NA) {
            f32x4 v = ((const f32x4*)emb)[i];
            u16x4 o = { f2h(v[0]), f2h(v[1]), f2h(v[2]), f2h(v[3]) };
            ((u16x4*)embB)[i] = o;
        } else if (i < NA + NB) {
            long j = i - NA; long flat = j * 4;
            int r = (int)(flat >> 8), e0 = (int)(flat & 255);
            int p = ((r & 511) << 2) | (r >> 9);
            f32x4 v = ((const f32x4*)Wih)[j];
            u16x4 o = { f2h(v[0]), f2h(v[1]), f2h(v[2]), f2h(v[3]) };
            *(u16x4*)(WihP + (size_t)p * D_E + e0) = o;
        } else if (i < NA + NB + NC) {
            long j = i - NA - NB; long flat = j * 4;
            int r = (int)(flat >> 9), k0 = (int)(flat & 511);
            int p = ((r & 511) << 2) | (r >> 9);
            f32x4 v = ((const f32x4*)Whh)[j];
            u16x4 o = { f2h(v[0]), f2h(v[1]), f2h(v[2]), f2h(v[3]) };
            *(u16x4*)(WhhP + (size_t)p * D_H + k0) = o;
        } else if (i < NA + NB + NC + ND) {
            int p = (int)(i - NA - NB - NC);
            int r = ((p & 3) << 9) | (p >> 2);
            biasP[p] = bih[r] + bhh[r];
        } else if (i < NA + NB + NC + ND + NE) {
            long j = i - NA - NB - NC - ND;
            f32x4 z = (f32x4)0.0f;
            store16_llc(hbuf0 + j * 8, z);
        } else if (i < NA + NB + NC + ND + NE + NF) {
            long j = i - NA - NB - NC - ND - NE;
            store_dword_llc(flags + j, 0);
        } else {
            long j = i - NA - NB - NC - ND - NE - NF;
            int t = (int)(j >> 8), b = (int)(j & 255);
            abT[(size_t)t * D_B + b] = abstracts[(size_t)b * D_T + t];
        }
    }
    asm volatile("s_waitcnt vmcnt(0)" ::: "memory");  // drain LLC stores
}

// ======================================================================
// egemm: E_gates[v][p] = sum_e embB[v][e] * WihP[p][e]   (fp16 MFMA)
// ======================================================================
__global__ __launch_bounds__(256) void egemm_kernel(
    const uint16_t* __restrict__ embB, const uint16_t* __restrict__ WihP,
    uint16_t* __restrict__ EG)
{
    int nt = blockIdx.x;            // 0..15
    int mt = blockIdx.y;            // 0..234
    int tid = threadIdx.x, lane = tid & 63, wv = tid >> 6;
    int v0 = mt * 128, n0 = nt * 128;
    __shared__ uint16_t As[128][40];
    __shared__ uint16_t Bs[128][40];
    f32x4 acc[4][4];
#pragma unroll
    for (int a = 0; a < 4; ++a)
#pragma unroll
        for (int bb = 0; bb < 4; ++bb) acc[a][bb] = (f32x4)0.0f;
    int wm = (wv >> 1) * 64, wn = (wv & 1) * 64;
    int row = tid >> 1, half = tid & 1;
    for (int kb = 0; kb < 8; ++kb) {
        int k0 = kb * 32;
        int vrow = v0 + row; if (vrow > D_V - 1) vrow = D_V - 1;
        const s16x8* pa = (const s16x8*)(embB + (size_t)vrow * D_E + k0 + half * 16);
        *(s16x8*)&As[row][half * 16]     = pa[0];
        *(s16x8*)&As[row][half * 16 + 8] = pa[1];
        const s16x8* pb = (const s16x8*)(WihP + (size_t)(n0 + row) * D_E + k0 + half * 16);
        *(s16x8*)&Bs[row][half * 16]     = pb[0];
        *(s16x8*)&Bs[row][half * 16 + 8] = pb[1];
        __syncthreads();
        int krow = (lane >> 4) * 8;
        f16x8 af[4], bfr[4];
#pragma unroll
        for (int i = 0; i < 4; ++i) af[i]  = *(const f16x8*)&As[wm + i * 16 + (lane & 15)][krow];
#pragma unroll
        for (int i = 0; i < 4; ++i) bfr[i] = *(const f16x8*)&Bs[wn + i * 16 + (lane & 15)][krow];
#pragma unroll
        for (int mi = 0; mi < 4; ++mi)
#pragma unroll
            for (int ni = 0; ni < 4; ++ni)
                acc[mi][ni] = __builtin_amdgcn_mfma_f32_16x16x32_f16(af[mi], bfr[ni], acc[mi][ni], 0, 0, 0);
        __syncthreads();
    }
#pragma unroll
    for (int mi = 0; mi < 4; ++mi) {
        int rbase = v0 + wm + mi * 16 + (lane >> 4) * 4;
#pragma unroll
        for (int ni = 0; ni < 4; ++ni) {
            int col = n0 + wn + ni * 16 + (lane & 15);
#pragma unroll
            for (int r = 0; r < 4; ++r) {
                int vr = rbase + r;
                if (vr < D_V) EG[(size_t)vr * D_G + col] = f2h(acc[mi][ni][r]);
            }
        }
    }
}

// ======================================================================
// lstm_seq: 64 WGs × 4 INDEPENDENT waves. Wave (wg,wv) owns batch rows
// [wv*64, wv*64+64) and the WG's 8 h-indices. h exchanged via LLC
// (sc0 sc1 bypass loads/stores), per-wave seqno flags, no barriers,
// no cache-maintenance ops.
// ======================================================================
__global__ __launch_bounds__(256, 1) void lstm_seq_kernel(
    const int* __restrict__ abT, const uint16_t* __restrict__ EG,
    const uint16_t* __restrict__ WhhP, const float* __restrict__ biasP,
    uint16_t* __restrict__ hbuf, int* __restrict__ flags,
    float* __restrict__ reps)
{
    const int wg = blockIdx.x;                 // 0..63
    const int tid = threadIdx.x, lane = tid & 63, wv = tid >> 6;
    __shared__ float gfull[256][33];           // wave-private row ranges
    __shared__ float c_st[8][256];
    __shared__ float rmax[8][256];
    __shared__ float bias_s[32];

    if (tid < 32) bias_s[tid] = biasP[wg * 32 + tid];
#pragma unroll
    for (int j = 0; j < 8; ++j) { c_st[j][tid] = 0.0f; rmax[j][tid] = -1e30f; }

    // resident B fragments: Whh slice [32 rows][512 k] fp16 (normal cached loads)
    const uint16_t* Wp = WhhP + (size_t)wg * 32 * D_H;
    f16x8 bq[2][16];
#pragma unroll
    for (int nt = 0; nt < 2; ++nt)
#pragma unroll
        for (int ks = 0; ks < 16; ++ks)
            bq[nt][ks] = *(const f16x8*)(Wp + (size_t)(nt * 16 + (lane & 15)) * D_H + ks * 32 + ((lane >> 4) * 8));
    __syncthreads();   // bias_s/bq ready; last barrier in the kernel

    const int b = tid;  // 0..255 (wave wv owns b in [wv*64, wv*64+64))
    for (int t = 0; t < D_T; ++t) {
        // ---- gather x-gates + bias into gfull[b][*] (cached loads, overlaps poll)
        int tok = abT[(size_t)t * D_B + b];
        const uint16_t* eg = EG + (size_t)tok * D_G + wg * 32;
        f16x8 g0 = *(const f16x8*)(eg);
        f16x8 g1 = *(const f16x8*)(eg + 8);
        f16x8 g2 = *(const f16x8*)(eg + 16);
        f16x8 g3 = *(const f16x8*)(eg + 24);
#pragma unroll
        for (int i = 0; i < 8; ++i) gfull[b][i]      = bias_s[i]      + (float)g0[i];
#pragma unroll
        for (int i = 0; i < 8; ++i) gfull[b][8 + i]  = bias_s[8 + i]  + (float)g1[i];
#pragma unroll
        for (int i = 0; i < 8; ++i) gfull[b][16 + i] = bias_s[16 + i] + (float)g2[i];
#pragma unroll
        for (int i = 0; i < 8; ++i) gfull[b][24 + i] = bias_s[24 + i] + (float)g3[i];

        // ---- wait for wave-row wv of ALL 64 WGs to have published step t
        if (t > 0) {
            const int* fp = flags + wv * 64 + lane;   // lane l ↦ WG l's wave-wv flag
            int guard = 0;
            while (true) {
                int f = load_flag_llc(fp);
                if (__all(f >= t)) break;
                if (++guard > (1 << 21)) break;   // bailout: wrong answer instead of hang
            }
        }

        // ---- gates += Whh_slice @ h_t  (h from LLC, 16-deep batched loads)
        const uint16_t* cur = hbuf + (size_t)(t & 1) * (D_B * D_H);
        f32x4 acc[4][2];
#pragma unroll
        for (int m = 0; m < 4; ++m) { acc[m][0] = (f32x4)0.0f; acc[m][1] = (f32x4)0.0f; }
#pragma unroll
        for (int mtt = 0; mtt < 4; ++mtt) {
            const uint16_t* base = cur + (size_t)((wv * 4 + mtt) * 16 + (lane & 15)) * D_H + ((lane >> 4) * 8);
            f16x8 A[16];
            load_h16_llc(base, A);
#pragma unroll
            for (int ks = 0; ks < 16; ++ks) {
                acc[mtt][0] = __builtin_amdgcn_mfma_f32_16x16x32_f16(A[ks], bq[0][ks], acc[mtt][0], 0, 0, 0);
                acc[mtt][1] = __builtin_amdgcn_mfma_f32_16x16x32_f16(A[ks], bq[1][ks], acc[mtt][1], 0, 0, 0);
            }
        }
        // ---- accumulate into gfull (wave-private rows; no barrier needed)
#pragma unroll
        for (int mtt = 0; mtt < 4; ++mtt) {
            int br = (wv * 4 + mtt) * 16 + (lane >> 4) * 4;
#pragma unroll
            for (int nt = 0; nt < 2; ++nt) {
                int n = nt * 16 + (lane & 15);
#pragma unroll
                for (int r = 0; r < 4; ++r) gfull[br + r][n] += acc[mtt][nt][r];
            }
        }

        // ---- pointwise LSTM cell + running max + h store (thread = batch b)
        f16x8 vh;
#pragma unroll
        for (int j = 0; j < 8; ++j) {
            float gi = gfull[b][j * 4 + 0];
            float gf = gfull[b][j * 4 + 1];
            float gg = gfull[b][j * 4 + 2];
            float go = gfull[b][j * 4 + 3];
            float c2 = sigm(gf) * c_st[j][b] + sigm(gi) * tanh_fast(gg);
            float h2 = sigm(go) * tanh_fast(c2);
            c_st[j][b] = c2;
            float rm = fmaxf(rmax[j][b], h2);
            if ((t & 31) == 31) {
                reps[(size_t)(t >> 5) * (D_B * D_H) + (size_t)b * D_H + wg * 8 + j] = rm;
                rm = -1e30f;
            }
            rmax[j][b] = rm;
            vh[j] = (_Float16)h2;
        }
        uint16_t* dst = hbuf + (size_t)((t + 1) & 1) * (D_B * D_H) + (size_t)b * D_H + wg * 8;
        store_h_llc(dst, vh);          // write-through to LLC + vmcnt(0)
        if (lane == 0)
            store_flag_llc(flags + wv * 64 + wg, t + 1);
    }
}

// ======================================================================
// predA: A[s][b][c] = tanh(sum_{k<=min(s,2)} reps[s-k,b,:]·W1[k,:,c] + b1[c])
// ======================================================================
__global__ __launch_bounds__(256) void predA_kernel(
    const float* __restrict__ reps, const float* __restrict__ W1,
    const float* __restrict__ b1, float* __restrict__ A, float* __restrict__ A0)
{
    int gw = blockIdx.x * 4 + (threadIdx.x >> 6);   // 0..4095
    int lane = threadIdx.x & 63;
    int s = gw >> 8, b = gw & 255;
    float accT[5] = {0, 0, 0, 0, 0};
    float acc0[5] = {0, 0, 0, 0, 0};
    for (int k = 0; k <= 2; ++k) {
        if (s - k < 0) break;
        const float* rp = reps + ((size_t)(s - k) * D_B + b) * D_H;
        const float* w  = W1 + (size_t)k * D_H * D_C;
        float part[5] = {0, 0, 0, 0, 0};
#pragma unroll
        for (int i = 0; i < 8; ++i) {
            int h = lane * 8 + i;
            float rv = rp[h];
#pragma unroll
            for (int c = 0; c < 5; ++c) part[c] += rv * w[h * 5 + c];
        }
#pragma unroll
        for (int c = 0; c < 5; ++c) { accT[c] += part[c]; if (k == 0) acc0[c] = part[c]; }
    }
#pragma unroll
    for (int m = 1; m < 64; m <<= 1)
#pragma unroll
        for (int c = 0; c < 5; ++c) {
            accT[c] += __shfl_xor(accT[c], m, 64);
            acc0[c] += __shfl_xor(acc0[c], m, 64);
        }
    if (lane == 0) {
#pragma unroll
        for (int c = 0; c < 5; ++c) A[((size_t)s * D_B + b) * D_C + c] = tanhf(accT[c] + b1[c]);
        if (s < 3)
#pragma unroll
            for (int c = 0; c < 5; ++c) A0[((size_t)s * D_B + b) * D_C + c] = tanhf(acc0[c] + b1[c]);
    }
}

// ======================================================================
// predOut: main i>=0: M[i] = sum_t A[t+i]@W2[t] + b2 ; fallback s<3 uses A0@W2[0]
// ======================================================================
__global__ __launch_bounds__(256) void predOut_kernel(
    const float* __restrict__ A, const float* __restrict__ A0,
    const float* __restrict__ W2, const float* __restrict__ b2,
    float* __restrict__ out)
{
    int g = blockIdx.x * 256 + threadIdx.x;   // 0..4095
    int b = g >> 4, s = g & 15;
    float v[5];
#pragma unroll
    for (int d = 0; d < 5; ++d) v[d] = b2[d];
    if (s < 3) {
        const float* Ar = A0 + ((size_t)s * D_B + b) * D_C;
#pragma unroll
        for (int c = 0; c < 5; ++c) {
            float a = Ar[c];
#pragma unroll
            for (int d = 0; d < 5; ++d) v[d] += a * W2[c * 5 + d];
        }
    } else {
        int i = s - 3;
        for (int tt = 0; tt < 4; ++tt) {
            const float* Ar = A + ((size_t)(tt + i) * D_B + b) * D_C;
            const float* w  = W2 + tt * 25;
#pragma unroll
            for (int c = 0; c < 5; ++c) {
                float a = Ar[c];
#pragma unroll
                for (int d = 0; d < 5; ++d) v[d] += a * w[c * 5 + d];
            }
        }
    }
    float m = v[0];
#pragma unroll
    for (int d = 1; d < 5; ++d) m = fmaxf(m, v[d]);
    float ssum = 0.0f;
#pragma unroll
    for (int d = 0; d < 5; ++d) ssum += expf(v[d] - m);
    float l = logf(ssum);
#pragma unroll
    for (int d = 0; d < 5; ++d) out[(size_t)b * 80 + d * 16 + s] = v[d] - m - l;
}

// ======================================================================
extern "C" void kernel_launch(void* const* d_in, const int* in_sizes, int n_in,
                              void* d_out, int out_size, void* d_ws, size_t ws_size,
                              hipStream_t stream)
{
    const int*   abstracts = (const int*)  d_in[0];
    const float* emb  = (const float*)d_in[1];
    const float* Wih  = (const float*)d_in[2];
    const float* Whh  = (const float*)d_in[3];
    const float* bih  = (const float*)d_in[4];
    const float* bhh  = (const float*)d_in[5];
    const float* W1   = (const float*)d_in[6];
    const float* b1   = (const float*)d_in[7];
    const float* W2   = (const float*)d_in[8];
    const float* b2   = (const float*)d_in[9];
    float* out = (float*)d_out;

    char* ws = (char*)d_ws;
    uint16_t* EG    = (uint16_t*)(ws + OFF_EG);
    uint16_t* embB  = (uint16_t*)(ws + OFF_EMB);
    uint16_t* WihP  = (uint16_t*)(ws + OFF_WIH);
    uint16_t* WhhP  = (uint16_t*)(ws + OFF_WHH);
    float*    biasP = (float*)   (ws + OFF_BIAS);
    uint16_t* hbuf  = (uint16_t*)(ws + OFF_HBUF);
    int*      flags = (int*)     (ws + OFF_FLAGS);
    float*    reps  = (float*)   (ws + OFF_REPS);
    float*    Abuf  = (float*)   (ws + OFF_A);
    float*    A0buf = (float*)   (ws + OFF_A0);
    int*      abT   = (int*)     (ws + OFF_ABT);

    prep_kernel<<<dim3(2048), dim3(256), 0, stream>>>(abstracts, emb, Wih, Whh, bih, bhh,
                                                      embB, WihP, WhhP, biasP, hbuf, flags, abT);
    egemm_kernel<<<dim3(16, 235), dim3(256), 0, stream>>>(embB, WihP, EG);
    lstm_seq_kernel<<<dim3(NWG), dim3(256), 0, stream>>>(abT, EG, WhhP, biasP,
                                                         hbuf, flags, reps);
    predA_kernel<<<dim3(1024), dim3(256), 0, stream>>>(reps, W1, b1, Abuf, A0buf);
    predOut_kernel<<<dim3(16), dim3(256), 0, stream>>>(Abuf, A0buf, W2, b2, out);
}